// Round 6
// baseline (293.614 us; speedup 1.0000x reference)
//
#include <hip/hip_runtime.h>

// ---------- common types / helpers ----------
typedef __attribute__((ext_vector_type(8))) short bf16x8;   // 8 bf16 = 4 VGPRs
typedef __attribute__((ext_vector_type(4))) float f32x4;
typedef __attribute__((ext_vector_type(4))) unsigned int u32x4;

// q pre-scale: softmax scale (1/sqrt(64)) * log2(e), so P = exp2(S) directly.
#define QSCALE 0.1803368801111243f

__device__ inline unsigned short f2bf(float f) {
  union { float f; unsigned u; } v; v.f = f;
  unsigned r = v.u + 0x7fffu + ((v.u >> 16) & 1u);   // RNE
  return (unsigned short)(r >> 16);
}

// pack two fp32 -> two bf16 (RNE) in one dword: low16 = bf(a), high16 = bf(b)
__device__ inline unsigned packbf2(float a, float b) {
  union { float f; unsigned u; } va, vb; va.f = a; vb.f = b;
  unsigned ta = va.u + 0x7fffu + ((va.u >> 16) & 1u);
  unsigned tb = vb.u + 0x7fffu + ((vb.u >> 16) & 1u);
  return __builtin_amdgcn_perm(tb, ta, 0x07060302);  // bytes [tb3 tb2 ta3 ta2]
}

// async global->LDS, 16 bytes per lane (flash_attn staging)
__device__ inline void async16(const void* g, void* l) {
  __builtin_amdgcn_global_load_lds(
      (const __attribute__((address_space(1))) unsigned int*)g,
      (__attribute__((address_space(3))) unsigned int*)l, 16, 0, 0);
}

// ---------- kernel 1: cast fp32 -> bf16 for WEIGHTS only (x is fused into gemm0) ----------
// qkv_w quads 442368, proj_w quads 147456 -> 589824 quads = 2304 blocks exactly.
__global__ __launch_bounds__(256) void cast_w(
    const float* __restrict__ wq, const float* __restrict__ wp,
    unsigned short* __restrict__ wqb, unsigned short* __restrict__ wpb)
{
  long i = (long)blockIdx.x * 256 + threadIdx.x;   // index over float4 quads
  const float* src; unsigned short* dst;
  if (i < 442368L) { src = wq + i * 4; dst = wqb + i * 4; }
  else             { long j = i - 442368L; src = wp + j * 4; dst = wpb + j * 4; }
  float4 v = *(const float4*)src;
  uint2 o;
  o.x = packbf2(v.x, v.y);
  o.y = packbf2(v.z, v.w);
  *(uint2*)dst = o;
}

// ---------- GEMM: C[m][n] = sum_k A[m][k] * Bt[n][k]  (fp32 acc) ----------
// Register-staged pipeline, single LDS buffer (R5 structure — R4 lesson: LDS bytes ARE
// the latency-hiding budget). MODE 0: A = x read as FP32 directly (cast fused into the
// staging path; conversion happens at ds_write time so the vmcnt wait stays after a
// full compute phase). B = pre-cast bf16 weights. MODE 1: A = bf16 attn-out, B = bf16.
template<int MODE>
__global__ __launch_bounds__(256) void gemm_bt(
    const float* __restrict__ Af, const unsigned short* __restrict__ A16,
    const unsigned short* __restrict__ Bt, const float* __restrict__ bias,
    unsigned short* __restrict__ oq, unsigned short* __restrict__ ok,
    unsigned short* __restrict__ ov, float* __restrict__ of)
{
  constexpr int K = 768;
  constexpr int BM = (MODE == 0) ? 128 : 64;   // block M-tile
  constexpr int MI = BM / 32;                  // per-wave m-tiles (4 or 2)
  constexpr int NA = (8 * BM) / 256;           // A stage 16B-slots per thread (4 or 2)
  __shared__ unsigned short As[8 * BM * 8];    // slot s = chunk*BM + row
  __shared__ unsigned short Bs[8192];
  const int t = threadIdx.x;
  const int w = t >> 6, lane = t & 63;
  const int quad = lane >> 4, l16 = lane & 15;
  const int bm = blockIdx.x, bn = blockIdx.y;
  const int wm = (w >> 1) * (BM / 2), wn = (w & 1) << 6;

  f32x4 acc[MI][4] = {};

  const unsigned short* Bg = Bt + (size_t)bn * 128 * K;

  // per-thread staging base pointers (constant across iters; k0 goes in the imm)
  const float* abasef[NA];          // MODE 0
  const unsigned short* abase16[NA]; // MODE 1
  const unsigned short* bbase[4];
#pragma unroll
  for (int i = 0; i < NA; i++) {
    int s = i * 256 + t;
    if (MODE == 0) abasef[i]  = Af  + (size_t)bm * BM * K + (size_t)(s & (BM - 1)) * K + (s / BM) * 8;
    else           abase16[i] = A16 + (size_t)bm * BM * K + (size_t)(s & (BM - 1)) * K + (s / BM) * 8;
  }
#pragma unroll
  for (int i = 0; i < 4; i++) {
    int s = i * 256 + t;
    bbase[i] = Bg + (size_t)(s & 127) * K + (s >> 7) * 8;
  }

  f32x4 raf[2 * NA];   // MODE 0: fp32 A staging
  u32x4 ra[NA];        // MODE 1: bf16 A staging
  u32x4 rb[4];
  auto fetch = [&](int k0) {
#pragma unroll
    for (int i = 0; i < NA; i++) {
      if (MODE == 0) {
        raf[2 * i]     = *(const f32x4*)(abasef[i] + k0);
        raf[2 * i + 1] = *(const f32x4*)(abasef[i] + k0 + 4);
      } else {
        ra[i] = *(const u32x4*)(abase16[i] + k0);
      }
    }
#pragma unroll
    for (int i = 0; i < 4; i++)  rb[i] = *(const u32x4*)(bbase[i] + k0);
  };

  fetch(0);   // prologue: tile 0 -> regs

#pragma unroll
  for (int it = 0; it < K / 64; it++) {
    __syncthreads();               // all waves done reading LDS (prev tile)
#pragma unroll
    for (int i = 0; i < NA; i++) {
      if (MODE == 0) {
        u32x4 wv;
        wv.x = packbf2(raf[2 * i].x,     raf[2 * i].y);
        wv.y = packbf2(raf[2 * i].z,     raf[2 * i].w);
        wv.z = packbf2(raf[2 * i + 1].x, raf[2 * i + 1].y);
        wv.w = packbf2(raf[2 * i + 1].z, raf[2 * i + 1].w);
        *(u32x4*)&As[(i * 256 + t) * 8] = wv;
      } else {
        *(u32x4*)&As[(i * 256 + t) * 8] = ra[i];
      }
    }
#pragma unroll
    for (int i = 0; i < 4; i++)  *(u32x4*)&Bs[(i * 256 + t) * 8] = rb[i];
    __syncthreads();               // tile it visible in LDS
    if (it < K / 64 - 1) fetch((it + 1) * 64);   // issue next loads, no wait

#pragma unroll
    for (int kk = 0; kk < 2; kk++) {
      bf16x8 a[MI], b[4];
#pragma unroll
      for (int mi = 0; mi < MI; mi++)
        a[mi] = *(const bf16x8*)&As[(((kk << 2) + quad) * BM + wm + (mi << 4) + l16) * 8];
#pragma unroll
      for (int ni = 0; ni < 4; ni++)
        b[ni] = *(const bf16x8*)&Bs[((((kk << 2) + quad) << 7) + wn + (ni << 4) + l16) * 8];
#pragma unroll
      for (int mi = 0; mi < MI; mi++)
#pragma unroll
        for (int ni = 0; ni < 4; ni++)
          acc[mi][ni] = __builtin_amdgcn_mfma_f32_16x16x32_bf16(a[mi], b[ni], acc[mi][ni], 0, 0, 0);
    }
  }

  // ---- epilogue ----  C/D layout: col = l16, row = quad*4 + reg
  if (MODE == 0) {
    const int three = (bn * 128) / 768;          // block-uniform (768 % 128 == 0)
#pragma unroll
    for (int ni = 0; ni < 4; ni++) {
      int n_g = bn * 128 + wn + (ni << 4) + l16;
      float bs = bias[n_g];
      int rem = n_g - three * 768;
      int h = rem >> 6, d = rem & 63;
#pragma unroll
      for (int mi = 0; mi < MI; mi++) {
#pragma unroll
        for (int r = 0; r < 4; r++) {
          int m_g = bm * BM + wm + (mi << 4) + (quad << 2) + r;
          int b_ = m_g >> 11, ntok = m_g & 2047;
          float v = acc[mi][ni][r] + bs;
          if (three == 0)
            oq[(((size_t)b_ * 12 + h) * 2048 + ntok) * 64 + d] = f2bf(v * QSCALE);
          else if (three == 1)
            ok[(((size_t)b_ * 12 + h) * 2048 + ntok) * 64 + d] = f2bf(v);
          else
            ov[(((size_t)b_ * 12 + h) * 64 + d) * 2048 + ntok] = f2bf(v);
        }
      }
    }
  } else {
#pragma unroll
    for (int ni = 0; ni < 4; ni++) {
      int n_g = bn * 128 + wn + (ni << 4) + l16;
      float bs = bias[n_g];
#pragma unroll
      for (int mi = 0; mi < MI; mi++) {
#pragma unroll
        for (int r = 0; r < 4; r++) {
          int m_g = bm * BM + wm + (mi << 4) + (quad << 2) + r;
          of[(size_t)m_g * 768 + n_g] = acc[mi][ni][r] + bs;
        }
      }
    }
  }
}

// ---------- kernel 3: flash attention, transposed-score + register-P ----------
// Grid (48 bh, 16 qt): same-bh blocks are 48 apart in linear ID == 0 mod 8 -> land on
// the same XCD, so each 512 KB K/V slab is fetched into one XCD's L2 once (was ~4x).
__global__ __launch_bounds__(256, 3) void flash_attn(
    const unsigned short* __restrict__ Qb, const unsigned short* __restrict__ Kb,
    const unsigned short* __restrict__ Vtb, unsigned short* __restrict__ Ob)
{
  __shared__ unsigned short Ks[2][4096];   // slot(c,kvslot) = K[g(kvslot)][c*8..+8]
  __shared__ unsigned short Vs[2][4096];   // slot(c,d)      = V^T[d][c*8..+8]
  const int t = threadIdx.x, w = t >> 6, lane = t & 63;
  const int quad = lane >> 4, l16 = lane & 15;
  const int bh = blockIdx.x, qt = blockIdx.y;
  const unsigned short* Qg = Qb + (size_t)bh * 2048 * 64;
  const unsigned short* Kg = Kb + (size_t)bh * 2048 * 64;
  const unsigned short* Vg = Vtb + (size_t)bh * 2048 * 64;   // [64][2048]

  bf16x8 bq[2][2];
#pragma unroll
  for (int u = 0; u < 2; u++) {
    int qrow = qt * 128 + w * 32 + u * 16 + l16;
#pragma unroll
    for (int h = 0; h < 2; h++)
      bq[u][h] = *(const bf16x8*)(Qg + (size_t)qrow * 64 + h * 32 + quad * 8);
  }

  const int s0 = t, s1 = 256 + t;
  auto gperm = [](int s) { return (s & 0x23) | ((s & 0x0c) << 1) | ((s & 0x10) >> 2); };
  const size_t koff0 = (size_t)gperm(s0 & 63) * 64 + (s0 >> 6) * 8;
  const size_t koff1 = (size_t)gperm(s1 & 63) * 64 + (s1 >> 6) * 8;
  const size_t voff0 = (size_t)(s0 & 63) * 2048 + (s0 >> 6) * 8;
  const size_t voff1 = (size_t)(s1 & 63) * 2048 + (s1 >> 6) * 8;

  float l_run[2] = {0.f, 0.f};
  f32x4 o_acc[2][4];
#pragma unroll
  for (int u = 0; u < 2; u++)
#pragma unroll
    for (int dt = 0; dt < 4; dt++) o_acc[u][dt] = (f32x4){0.f, 0.f, 0.f, 0.f};

  async16(Kg + koff0, &Ks[0][s0 * 8]);
  async16(Kg + koff1, &Ks[0][s1 * 8]);
  async16(Vg + voff0, &Vs[0][s0 * 8]);
  async16(Vg + voff1, &Vs[0][s1 * 8]);

  for (int kt = 0; kt < 32; kt++) {
    const int p = kt & 1;
    __syncthreads();
    if (kt < 31) {
      const unsigned short* Kn = Kg + (size_t)(kt + 1) * 4096;
      const unsigned short* Vn = Vg + (size_t)(kt + 1) * 64;
      async16(Kn + koff0, &Ks[p ^ 1][s0 * 8]);
      async16(Kn + koff1, &Ks[p ^ 1][s1 * 8]);
      async16(Vn + voff0, &Vs[p ^ 1][s0 * 8]);
      async16(Vn + voff1, &Vs[p ^ 1][s1 * 8]);
    }
    const unsigned short* Kp = &Ks[p][0];
    const unsigned short* Vp = &Vs[p][0];

    f32x4 sv[2][4];
#pragma unroll
    for (int nt = 0; nt < 4; nt++) {
      bf16x8 k0 = *(const bf16x8*)&Kp[((quad) * 64 + nt * 16 + l16) * 8];
      bf16x8 k1 = *(const bf16x8*)&Kp[((4 + quad) * 64 + nt * 16 + l16) * 8];
#pragma unroll
      for (int u = 0; u < 2; u++) {
        f32x4 s_ = {0.f, 0.f, 0.f, 0.f};
        s_ = __builtin_amdgcn_mfma_f32_16x16x32_bf16(k0, bq[u][0], s_, 0, 0, 0);
        s_ = __builtin_amdgcn_mfma_f32_16x16x32_bf16(k1, bq[u][1], s_, 0, 0, 0);
        sv[u][nt] = s_;
      }
    }

    union { unsigned u32[8]; bf16x8 v[2]; } pk[2];
#pragma unroll
    for (int u = 0; u < 2; u++) {
#pragma unroll
      for (int nt = 0; nt < 4; nt++) {
        float p0 = __builtin_amdgcn_exp2f(sv[u][nt][0]);
        float p1 = __builtin_amdgcn_exp2f(sv[u][nt][1]);
        float p2 = __builtin_amdgcn_exp2f(sv[u][nt][2]);
        float p3 = __builtin_amdgcn_exp2f(sv[u][nt][3]);
        l_run[u] += (p0 + p1) + (p2 + p3);
        pk[u].u32[nt * 2]     = packbf2(p0, p1);
        pk[u].u32[nt * 2 + 1] = packbf2(p2, p3);
      }
    }

#pragma unroll
    for (int cc = 0; cc < 2; cc++) {
#pragma unroll
      for (int dt = 0; dt < 4; dt++) {
        bf16x8 a = *(const bf16x8*)&Vp[((cc * 4 + quad) * 64 + dt * 16 + l16) * 8];
#pragma unroll
        for (int u = 0; u < 2; u++)
          o_acc[u][dt] = __builtin_amdgcn_mfma_f32_16x16x32_bf16(a, pk[u].v[cc], o_acc[u][dt], 0, 0, 0);
      }
    }
  }

  float linv[2];
#pragma unroll
  for (int u = 0; u < 2; u++) {
    float l = l_run[u];
    l += __shfl_xor(l, 16, 64);
    l += __shfl_xor(l, 32, 64);
    linv[u] = 1.f / l;
  }

  const int b_ = bh / 12, h = bh - b_ * 12;
#pragma unroll
  for (int u = 0; u < 2; u++) {
    int tok = qt * 128 + w * 32 + u * 16 + l16;
    size_t rowbase = ((size_t)b_ * 2048 + tok) * 768 + h * 64;
#pragma unroll
    for (int dt = 0; dt < 4; dt++) {
#pragma unroll
      for (int pr = 0; pr < 2; pr++) {
        float v0 = o_acc[u][dt][pr * 2] * linv[u];
        float v1 = o_acc[u][dt][pr * 2 + 1] * linv[u];
        int d = dt * 16 + quad * 4 + pr * 2;
        *(unsigned*)&Ob[rowbase + d] = packbf2(v0, v1);
      }
    }
  }
}

// ---------- launch ----------
extern "C" void kernel_launch(void* const* d_in, const int* in_sizes, int n_in,
                              void* d_out, int out_size, void* d_ws, size_t ws_size,
                              hipStream_t stream) {
  const float* x      = (const float*)d_in[0];
  const float* qkv_w  = (const float*)d_in[1];
  const float* qkv_b  = (const float*)d_in[2];
  const float* proj_w = (const float*)d_in[3];
  const float* proj_b = (const float*)d_in[4];
  float* out = (float*)d_out;

  unsigned short* ws  = (unsigned short*)d_ws;
  unsigned short* wqb = ws;                  // 1769472  qkv_w bf16 [2304][768]
  unsigned short* wpb = wqb + 1769472;       // 589824   proj_w bf16 [768][768]
  unsigned short* qb  = wpb + 589824;        // 6291456  q bf16 [B,H,N,D] (pre-scaled)
  unsigned short* kb  = qb + 6291456;        // 6291456  k bf16 [B,H,N,D]
  unsigned short* vtb = kb + 6291456;        // 6291456  v bf16 [B,H,D,N] (transposed)
  unsigned short* ao  = vtb + 6291456;       // 6291456  attn out bf16 [8192][768]

  cast_w<<<2304, 256, 0, stream>>>(qkv_w, proj_w, wqb, wpb);
  gemm_bt<0><<<dim3(64, 18), 256, 0, stream>>>(x, nullptr, wqb, qkv_b, qb, kb, vtb, nullptr);
  flash_attn<<<dim3(48, 16), 256, 0, stream>>>(qb, kb, vtb, ao);
  gemm_bt<1><<<dim3(128, 6), 256, 0, stream>>>(nullptr, ao, wpb, proj_b, nullptr, nullptr, nullptr, out);
}

// Round 7
// 237.222 us; speedup vs baseline: 1.2377x; 1.2377x over previous
//
#include <hip/hip_runtime.h>

// ---------- common types / helpers ----------
typedef __attribute__((ext_vector_type(8))) short bf16x8;   // 8 bf16 = 4 VGPRs
typedef __attribute__((ext_vector_type(4))) float f32x4;
typedef __attribute__((ext_vector_type(4))) unsigned int u32x4;

// q pre-scale: softmax scale (1/sqrt(64)) * log2(e), so P = exp2(S) directly.
#define QSCALE 0.1803368801111243f

__device__ inline unsigned short f2bf(float f) {
  union { float f; unsigned u; } v; v.f = f;
  unsigned r = v.u + 0x7fffu + ((v.u >> 16) & 1u);   // RNE
  return (unsigned short)(r >> 16);
}

// pack two fp32 -> two bf16 (RNE) in one dword: low16 = bf(a), high16 = bf(b)
__device__ inline unsigned packbf2(float a, float b) {
  union { float f; unsigned u; } va, vb; va.f = a; vb.f = b;
  unsigned ta = va.u + 0x7fffu + ((va.u >> 16) & 1u);
  unsigned tb = vb.u + 0x7fffu + ((vb.u >> 16) & 1u);
  return __builtin_amdgcn_perm(tb, ta, 0x07060302);  // bytes [tb3 tb2 ta3 ta2]
}

// async global->LDS, 16 bytes per lane (flash_attn staging)
__device__ inline void async16(const void* g, void* l) {
  __builtin_amdgcn_global_load_lds(
      (const __attribute__((address_space(1))) unsigned int*)g,
      (__attribute__((address_space(3))) unsigned int*)l, 16, 0, 0);
}

// ================== FRAGMENT-MAJOR ("swizzled") LAYOUT ==================
// For a bf16 matrix M[R][768]: rows grouped by 64 (g), K in 8-elem chunks, 4 chunks
// per MFMA step (cg = 0..23). 16B slot index:
//   slot = ((g*24 + cg)*4 + mi)*64 + quad*16 + l16
// holds M[g*64 + mi*16 + l16][cg*32 + quad*8 .. +8].
// A wave's MFMA fragment (fixed g, cg, mi) = 64 consecutive slots -> one coalesced
// 1KB global_load_dwordx4 per lane. GEMMs need NO LDS and NO barriers.
// Strides in shorts: group = 49152, cg-step = 2048, mi = 512.

// ---------- swizzle kernels (replace the cast kernels; same bytes moved) ----------
__device__ inline void swz_one(const float* __restrict__ src, unsigned short* __restrict__ dst,
                               int idx) {
  int l16 = idx & 15, quad = (idx >> 4) & 3, mi = (idx >> 6) & 3;
  int rest = idx >> 8;
  int cg = rest % 24, g = rest / 24;
  int row = g * 64 + mi * 16 + l16;
  int k = cg * 32 + quad * 8;
  const float* s = src + (size_t)row * 768 + k;
  float4 v0 = *(const float4*)s, v1 = *(const float4*)(s + 4);
  u32x4 o;
  o.x = packbf2(v0.x, v0.y); o.y = packbf2(v0.z, v0.w);
  o.z = packbf2(v1.x, v1.y); o.w = packbf2(v1.z, v1.w);
  *(u32x4*)(dst + (size_t)idx * 8) = o;
}

// x [8192][768] fp32 -> xs swizzled bf16. slots = 786432 -> 3072 blocks.
__global__ __launch_bounds__(256) void swz_x(const float* __restrict__ x,
                                             unsigned short* __restrict__ xs) {
  swz_one(x, xs, blockIdx.x * 256 + threadIdx.x);
}

// qkv_w [2304][768] (221184 slots) + proj_w [768][768] (73728 slots) -> 1152 blocks.
__global__ __launch_bounds__(256) void swz_w(const float* __restrict__ wq,
                                             const float* __restrict__ wp,
                                             unsigned short* __restrict__ wqs,
                                             unsigned short* __restrict__ wps) {
  int idx = blockIdx.x * 256 + threadIdx.x;
  if (idx < 221184) swz_one(wq, wqs, idx);
  else              swz_one(wp, wps, idx - 221184);
}

// ---------- GEMM, barrier-free: C[m][n] = sum_k A[m][k]*Bt[n][k], both swizzled ----------
// MODE 0 (qkv): block 128x128, waves 2x2, acc 4x4; grid (64,18).
//   Epilogue: +bias, q*=QSCALE, scatter q,k->[B,H,N,D], v->[B,H,D,N].
// MODE 1 (proj): block 64x128, waves 1x4 (each 64x32), acc 4x2; grid (128,6).
//   Epilogue: +bias, fp32 out [8192][768].
// Per cg-step: MI+NI coalesced 1KB fragment loads + MI*NI MFMA. Register double-buffer,
// no LDS, no __syncthreads -> waves pipeline independently (the m97 barrier drain is gone).
template<int MODE>
__global__ __launch_bounds__(256, MODE == 0 ? 3 : 4) void gemm_swz(
    const unsigned short* __restrict__ A, const unsigned short* __restrict__ B,
    const float* __restrict__ bias,
    unsigned short* __restrict__ oq, unsigned short* __restrict__ ok,
    unsigned short* __restrict__ ov, float* __restrict__ of)
{
  constexpr int NI = (MODE == 0) ? 4 : 2;
  const int t = threadIdx.x, w = t >> 6, lane = t & 63;
  const int quad = lane >> 4, l16 = lane & 15;
  const int bm = blockIdx.x, bn = blockIdx.y;

  const int gA = (MODE == 0) ? (bm * 2 + (w >> 1)) : bm;
  const unsigned short* Ab = A + (size_t)gA * 49152 + (size_t)lane * 8;

  const unsigned short* Bb[NI];
#pragma unroll
  for (int ni = 0; ni < NI; ni++) {
    int n_base = bn * 128 + ((MODE == 0) ? (w & 1) * 64 : w * 32) + ni * 16;
    Bb[ni] = B + (size_t)(n_base >> 6) * 49152 + (size_t)((n_base >> 4) & 3) * 512
               + (size_t)lane * 8;
  }

  f32x4 acc[4][NI] = {};
  bf16x8 af[2][4], bf_[2][NI];

#pragma unroll
  for (int mi = 0; mi < 4; mi++) af[0][mi] = *(const bf16x8*)(Ab + mi * 512);
#pragma unroll
  for (int ni = 0; ni < NI; ni++) bf_[0][ni] = *(const bf16x8*)(Bb[ni]);

#pragma unroll
  for (int cg = 0; cg < 24; cg++) {
    const int cur = cg & 1;
    if (cg < 23) {   // prefetch next step's fragments (WAR-safe via dbuf)
#pragma unroll
      for (int mi = 0; mi < 4; mi++)
        af[cur ^ 1][mi] = *(const bf16x8*)(Ab + (cg + 1) * 2048 + mi * 512);
#pragma unroll
      for (int ni = 0; ni < NI; ni++)
        bf_[cur ^ 1][ni] = *(const bf16x8*)(Bb[ni] + (cg + 1) * 2048);
    }
#pragma unroll
    for (int mi = 0; mi < 4; mi++)
#pragma unroll
      for (int ni = 0; ni < NI; ni++)
        acc[mi][ni] = __builtin_amdgcn_mfma_f32_16x16x32_bf16(af[cur][mi], bf_[cur][ni],
                                                              acc[mi][ni], 0, 0, 0);
  }

  // ---- epilogue ----  C/D layout: col = l16, row = quad*4 + r
  if (MODE == 0) {
    const int three = (bn * 128) / 768;          // block-uniform (768 % 128 == 0)
#pragma unroll
    for (int ni = 0; ni < NI; ni++) {
      int n_g = bn * 128 + (w & 1) * 64 + ni * 16 + l16;
      float bs = bias[n_g];
      int rem = n_g - three * 768;
      int h = rem >> 6, d = rem & 63;
#pragma unroll
      for (int mi = 0; mi < 4; mi++) {
#pragma unroll
        for (int r = 0; r < 4; r++) {
          int m_g = gA * 64 + mi * 16 + (quad << 2) + r;
          int b_ = m_g >> 11, ntok = m_g & 2047;
          float v = acc[mi][ni][r] + bs;
          if (three == 0)
            oq[(((size_t)b_ * 12 + h) * 2048 + ntok) * 64 + d] = f2bf(v * QSCALE);
          else if (three == 1)
            ok[(((size_t)b_ * 12 + h) * 2048 + ntok) * 64 + d] = f2bf(v);
          else
            ov[(((size_t)b_ * 12 + h) * 64 + d) * 2048 + ntok] = f2bf(v);
        }
      }
    }
  } else {
#pragma unroll
    for (int ni = 0; ni < NI; ni++) {
      int n_g = bn * 128 + w * 32 + ni * 16 + l16;
      float bs = bias[n_g];
#pragma unroll
      for (int mi = 0; mi < 4; mi++) {
#pragma unroll
        for (int r = 0; r < 4; r++) {
          int m_g = bm * 64 + mi * 16 + (quad << 2) + r;
          of[(size_t)m_g * 768 + n_g] = acc[mi][ni][r] + bs;
        }
      }
    }
  }
}

// ---------- flash attention: transposed-score + register-P; output -> SWIZZLED ao ----------
// Grid (48 bh, 16 qt): same-bh blocks 48 apart == 0 mod 8 -> same XCD (K/V L2 locality).
// Epilogue writes O directly in fragment-major layout so gemm1 is barrier-free too.
__global__ __launch_bounds__(256, 3) void flash_attn(
    const unsigned short* __restrict__ Qb, const unsigned short* __restrict__ Kb,
    const unsigned short* __restrict__ Vtb, unsigned short* __restrict__ aos)
{
  __shared__ unsigned short Ks[2][4096];   // slot(c,kvslot) = K[g(kvslot)][c*8..+8]
  __shared__ unsigned short Vs[2][4096];   // slot(c,d)      = V^T[d][c*8..+8]
  const int t = threadIdx.x, w = t >> 6, lane = t & 63;
  const int quad = lane >> 4, l16 = lane & 15;
  const int bh = blockIdx.x, qt = blockIdx.y;
  const unsigned short* Qg = Qb + (size_t)bh * 2048 * 64;
  const unsigned short* Kg = Kb + (size_t)bh * 2048 * 64;
  const unsigned short* Vg = Vtb + (size_t)bh * 2048 * 64;   // [64][2048]

  bf16x8 bq[2][2];
#pragma unroll
  for (int u = 0; u < 2; u++) {
    int qrow = qt * 128 + w * 32 + u * 16 + l16;
#pragma unroll
    for (int h = 0; h < 2; h++)
      bq[u][h] = *(const bf16x8*)(Qg + (size_t)qrow * 64 + h * 32 + quad * 8);
  }

  const int s0 = t, s1 = 256 + t;
  auto gperm = [](int s) { return (s & 0x23) | ((s & 0x0c) << 1) | ((s & 0x10) >> 2); };
  const size_t koff0 = (size_t)gperm(s0 & 63) * 64 + (s0 >> 6) * 8;
  const size_t koff1 = (size_t)gperm(s1 & 63) * 64 + (s1 >> 6) * 8;
  const size_t voff0 = (size_t)(s0 & 63) * 2048 + (s0 >> 6) * 8;
  const size_t voff1 = (size_t)(s1 & 63) * 2048 + (s1 >> 6) * 8;

  float l_run[2] = {0.f, 0.f};
  f32x4 o_acc[2][4];
#pragma unroll
  for (int u = 0; u < 2; u++)
#pragma unroll
    for (int dt = 0; dt < 4; dt++) o_acc[u][dt] = (f32x4){0.f, 0.f, 0.f, 0.f};

  async16(Kg + koff0, &Ks[0][s0 * 8]);
  async16(Kg + koff1, &Ks[0][s1 * 8]);
  async16(Vg + voff0, &Vs[0][s0 * 8]);
  async16(Vg + voff1, &Vs[0][s1 * 8]);

  for (int kt = 0; kt < 32; kt++) {
    const int p = kt & 1;
    __syncthreads();
    if (kt < 31) {
      const unsigned short* Kn = Kg + (size_t)(kt + 1) * 4096;
      const unsigned short* Vn = Vg + (size_t)(kt + 1) * 64;
      async16(Kn + koff0, &Ks[p ^ 1][s0 * 8]);
      async16(Kn + koff1, &Ks[p ^ 1][s1 * 8]);
      async16(Vn + voff0, &Vs[p ^ 1][s0 * 8]);
      async16(Vn + voff1, &Vs[p ^ 1][s1 * 8]);
    }
    const unsigned short* Kp = &Ks[p][0];
    const unsigned short* Vp = &Vs[p][0];

    f32x4 sv[2][4];
#pragma unroll
    for (int nt = 0; nt < 4; nt++) {
      bf16x8 k0 = *(const bf16x8*)&Kp[((quad) * 64 + nt * 16 + l16) * 8];
      bf16x8 k1 = *(const bf16x8*)&Kp[((4 + quad) * 64 + nt * 16 + l16) * 8];
#pragma unroll
      for (int u = 0; u < 2; u++) {
        f32x4 s_ = {0.f, 0.f, 0.f, 0.f};
        s_ = __builtin_amdgcn_mfma_f32_16x16x32_bf16(k0, bq[u][0], s_, 0, 0, 0);
        s_ = __builtin_amdgcn_mfma_f32_16x16x32_bf16(k1, bq[u][1], s_, 0, 0, 0);
        sv[u][nt] = s_;
      }
    }

    union { unsigned u32[8]; bf16x8 v[2]; } pk[2];
#pragma unroll
    for (int u = 0; u < 2; u++) {
#pragma unroll
      for (int nt = 0; nt < 4; nt++) {
        float p0 = __builtin_amdgcn_exp2f(sv[u][nt][0]);
        float p1 = __builtin_amdgcn_exp2f(sv[u][nt][1]);
        float p2 = __builtin_amdgcn_exp2f(sv[u][nt][2]);
        float p3 = __builtin_amdgcn_exp2f(sv[u][nt][3]);
        l_run[u] += (p0 + p1) + (p2 + p3);
        pk[u].u32[nt * 2]     = packbf2(p0, p1);
        pk[u].u32[nt * 2 + 1] = packbf2(p2, p3);
      }
    }

#pragma unroll
    for (int cc = 0; cc < 2; cc++) {
#pragma unroll
      for (int dt = 0; dt < 4; dt++) {
        bf16x8 a = *(const bf16x8*)&Vp[((cc * 4 + quad) * 64 + dt * 16 + l16) * 8];
#pragma unroll
        for (int u = 0; u < 2; u++)
          o_acc[u][dt] = __builtin_amdgcn_mfma_f32_16x16x32_bf16(a, pk[u].v[cc], o_acc[u][dt], 0, 0, 0);
      }
    }
  }

  float linv[2];
#pragma unroll
  for (int u = 0; u < 2; u++) {
    float l = l_run[u];
    l += __shfl_xor(l, 16, 64);
    l += __shfl_xor(l, 32, 64);
    linv[u] = 1.f / l;
  }

  // epilogue: ao row = b_*2048 + tok, col = h*64 + d; write in fragment-major layout.
  // g = row>>6 = b_*32 + qt*2 + (w>>1);  mi = (row>>4)&3 = (w*2+u)&3;  l16 = row&15.
  // col = h*64 + dt*16 + quad*4 + pr*2 + {0,1}:
  //   cg = h*2 + (dt>>1); cq = (dt&1)*2 + (quad>>1); j = (quad&1)*4 + pr*2.
  const int b_ = bh / 12, h = bh - b_ * 12;
  const int g_ = b_ * 32 + qt * 2 + (w >> 1);
#pragma unroll
  for (int u = 0; u < 2; u++) {
    const int mi = (w * 2 + u) & 3;
    unsigned short* base = aos + (size_t)g_ * 49152 + mi * 512 + l16 * 8;
#pragma unroll
    for (int dt = 0; dt < 4; dt++) {
      int cg = h * 2 + (dt >> 1);
      int cq = (dt & 1) * 2 + (quad >> 1);
#pragma unroll
      for (int pr = 0; pr < 2; pr++) {
        float v0 = o_acc[u][dt][pr * 2] * linv[u];
        float v1 = o_acc[u][dt][pr * 2 + 1] * linv[u];
        int j = (quad & 1) * 4 + pr * 2;
        *(unsigned*)(base + cg * 2048 + cq * 128 + j) = packbf2(v0, v1);
      }
    }
  }
}

// ---------- launch ----------
extern "C" void kernel_launch(void* const* d_in, const int* in_sizes, int n_in,
                              void* d_out, int out_size, void* d_ws, size_t ws_size,
                              hipStream_t stream) {
  const float* x      = (const float*)d_in[0];
  const float* qkv_w  = (const float*)d_in[1];
  const float* qkv_b  = (const float*)d_in[2];
  const float* proj_w = (const float*)d_in[3];
  const float* proj_b = (const float*)d_in[4];
  float* out = (float*)d_out;

  unsigned short* ws  = (unsigned short*)d_ws;
  unsigned short* wqs = ws;                  // 1769472  qkv_w  swizzled bf16
  unsigned short* wps = wqs + 1769472;       // 589824   proj_w swizzled bf16
  unsigned short* xs  = wps + 589824;        // 6291456  x      swizzled bf16
  unsigned short* qb  = xs + 6291456;        // 6291456  q bf16 [B,H,N,D] (pre-scaled)
  unsigned short* kb  = qb + 6291456;        // 6291456  k bf16 [B,H,N,D]
  unsigned short* vtb = kb + 6291456;        // 6291456  v bf16 [B,H,D,N] (transposed)
  unsigned short* aos = vtb + 6291456;       // 6291456  attn-out swizzled bf16

  swz_w<<<1152, 256, 0, stream>>>(qkv_w, proj_w, wqs, wps);
  swz_x<<<3072, 256, 0, stream>>>(x, xs);
  gemm_swz<0><<<dim3(64, 18), 256, 0, stream>>>(xs, wqs, qkv_b, qb, kb, vtb, nullptr);
  flash_attn<<<dim3(48, 16), 256, 0, stream>>>(qb, kb, vtb, aos);
  gemm_swz<1><<<dim3(128, 6), 256, 0, stream>>>(aos, wps, proj_b, nullptr, nullptr, nullptr, out);
}